// Round 1
// baseline (3692.196 us; speedup 1.0000x reference)
//
#include <hip/hip_runtime.h>
#include <cstdint>
#include <cstddef>

#define NB 256   // batch
#define NT 512   // time steps
#define ND 64    // input dim
#define NH 512   // hidden dim

typedef __attribute__((ext_vector_type(8))) short short8;
typedef __attribute__((ext_vector_type(4))) float f32x4;

__device__ __forceinline__ unsigned short f2bf(float f) {
  union { float f; uint32_t u; } v; v.f = f;
  uint32_t u = v.u;
  return (unsigned short)((u + 0x7FFFu + ((u >> 16) & 1u)) >> 16);  // RNE
}
__device__ __forceinline__ float bf2f(unsigned short b) {
  union { uint32_t u; float f; } v; v.u = ((uint32_t)b) << 16;
  return v.f;
}

// One-time prep: split fp32 weights into bf16 hi/lo planes, combine biases,
// init out with b_ho.
__global__ void prep_kernel(const float* __restrict__ whh, const float* __restrict__ wih,
                            const float* __restrict__ bih, const float* __restrict__ bhh,
                            const float* __restrict__ bho, float* __restrict__ out,
                            unsigned short* __restrict__ whh_hi, unsigned short* __restrict__ whh_lo,
                            unsigned short* __restrict__ wih_hi, unsigned short* __restrict__ wih_lo,
                            float* __restrict__ bias) {
  int i = blockIdx.x * 256 + threadIdx.x;
  if (i < NH * NH) {
    float w = whh[i];
    unsigned short hb = f2bf(w);
    whh_hi[i] = hb;
    whh_lo[i] = f2bf(w - bf2f(hb));
  }
  if (i < NH * ND) {
    float w = wih[i];
    unsigned short hb = f2bf(w);
    wih_hi[i] = hb;
    wih_lo[i] = f2bf(w - bf2f(hb));
  }
  if (i < NH) bias[i] = bih[i] + bhh[i];
  if (i < NB * NT) out[i] = bho[0];
}

// One timestep: h_new = tanh([h | x_t] @ [W_hh | W_ih]^T + bias), fused
// out-partial (h_new . W_ho) via shuffle reduce + atomicAdd.
// Grid: 256 blocks = 16 batch-groups (16 rows) x 16 H-slices (32 cols).
// Block: 128 threads = 2 waves, each wave owns one 16-wide N-tile.
__global__ __launch_bounds__(128) void rnn_step(
    const unsigned short* __restrict__ whh_hi, const unsigned short* __restrict__ whh_lo,
    const unsigned short* __restrict__ wih_hi, const unsigned short* __restrict__ wih_lo,
    const float* __restrict__ bias, const float* __restrict__ x,
    const float* __restrict__ who,
    const unsigned short* __restrict__ hprev_hi, const unsigned short* __restrict__ hprev_lo,
    unsigned short* __restrict__ hnext_hi, unsigned short* __restrict__ hnext_lo,
    float* __restrict__ out, int t)
{
  const int bid  = blockIdx.x;
  const int bg   = bid >> 4;            // batch group (16 rows each)
  const int sl   = bid & 15;            // H slice (32 cols each)
  const int wv   = threadIdx.x >> 6;    // wave 0/1
  const int lane = threadIdx.x & 63;
  const int lm   = lane & 15;           // m (A) / n (B) index within tile
  const int lk   = (lane >> 4) * 8;     // k offset within 32-wide K tile
  const int bm   = bg * 16;
  const int n0   = sl * 32 + wv * 16;

  // Three independent accumulators (one per split product) to break the
  // MFMA dependency chain.
  f32x4 acc_hh = {0.f, 0.f, 0.f, 0.f};
  f32x4 acc_hl = {0.f, 0.f, 0.f, 0.f};
  f32x4 acc_lh = {0.f, 0.f, 0.f, 0.f};

  // A-frag (h): lane l holds A[m=l&15][k=(l>>4)*8+e] -> 16B contiguous load
  const unsigned short* ahp = hprev_hi + (size_t)(bm + lm) * NH + lk;
  const unsigned short* alp = hprev_lo + (size_t)(bm + lm) * NH + lk;
  // B-frag (W_hh^T): lane l holds B[k][n=l&15] = Whh[n0+lm][k] -> contiguous
  const unsigned short* bhp = whh_hi + (size_t)(n0 + lm) * NH + lk;
  const unsigned short* blp = whh_lo + (size_t)(n0 + lm) * NH + lk;

#pragma unroll
  for (int kt = 0; kt < NH / 32; ++kt) {
    short8 ah = *(const short8*)(ahp + kt * 32);
    short8 al = *(const short8*)(alp + kt * 32);
    short8 bh = *(const short8*)(bhp + kt * 32);
    short8 bl = *(const short8*)(blp + kt * 32);
    acc_hh = __builtin_amdgcn_mfma_f32_16x16x32_bf16(ah, bh, acc_hh, 0, 0, 0);
    acc_hl = __builtin_amdgcn_mfma_f32_16x16x32_bf16(ah, bl, acc_hl, 0, 0, 0);
    acc_lh = __builtin_amdgcn_mfma_f32_16x16x32_bf16(al, bh, acc_lh, 0, 0, 0);
  }

  // x part: 2 extra K-tiles (D=64), fp32 -> split bf16 in-register
  const float* xp = x + ((size_t)(bm + lm) * NT + t) * ND + lk;
  const unsigned short* bxh = wih_hi + (size_t)(n0 + lm) * ND + lk;
  const unsigned short* bxl = wih_lo + (size_t)(n0 + lm) * ND + lk;
#pragma unroll
  for (int xt = 0; xt < 2; ++xt) {
    float xv[8];
    *(f32x4*)&xv[0] = *(const f32x4*)(xp + xt * 32);
    *(f32x4*)&xv[4] = *(const f32x4*)(xp + xt * 32 + 4);
    short8 axh, axl;
#pragma unroll
    for (int e = 0; e < 8; ++e) {
      unsigned short hb = f2bf(xv[e]);
      axh[e] = (short)hb;
      axl[e] = (short)f2bf(xv[e] - bf2f(hb));
    }
    short8 bh = *(const short8*)(bxh + xt * 32);
    short8 bl = *(const short8*)(bxl + xt * 32);
    acc_hh = __builtin_amdgcn_mfma_f32_16x16x32_bf16(axh, bh, acc_hh, 0, 0, 0);
    acc_hl = __builtin_amdgcn_mfma_f32_16x16x32_bf16(axh, bl, acc_hl, 0, 0, 0);
    acc_lh = __builtin_amdgcn_mfma_f32_16x16x32_bf16(axl, bh, acc_lh, 0, 0, 0);
  }

  // Epilogue. D layout (measured): lane holds D[m=(lane>>4)*4+r][n=lane&15]
  const int n = n0 + lm;
  const float bv = bias[n];
  const float wo = who[n];
  float po[4];
#pragma unroll
  for (int r = 0; r < 4; ++r) {
    float pre = acc_hh[r] + acc_hl[r] + acc_lh[r] + bv;
    float hval = tanhf(pre);
    int m = (lane >> 4) * 4 + r;
    size_t idx = (size_t)(bm + m) * NH + n;
    unsigned short hb = f2bf(hval);
    hnext_hi[idx] = hb;
    hnext_lo[idx] = f2bf(hval - bf2f(hb));
    po[r] = hval * wo;
  }
  // reduce over the 16 n-lanes within each lane group
#pragma unroll
  for (int s = 1; s < 16; s <<= 1) {
#pragma unroll
    for (int r = 0; r < 4; ++r) po[r] += __shfl_xor(po[r], s, 64);
  }
  if (lm == 0) {
#pragma unroll
    for (int r = 0; r < 4; ++r) {
      int m = (lane >> 4) * 4 + r;
      atomicAdd(&out[(size_t)(bm + m) * NT + t], po[r]);
    }
  }
}

extern "C" void kernel_launch(void* const* d_in, const int* in_sizes, int n_in,
                              void* d_out, int out_size, void* d_ws, size_t ws_size,
                              hipStream_t stream) {
  const float* x   = (const float*)d_in[0];
  const float* wih = (const float*)d_in[1];
  const float* whh = (const float*)d_in[2];
  const float* bih = (const float*)d_in[3];
  const float* bhh = (const float*)d_in[4];
  const float* who = (const float*)d_in[5];
  const float* bho = (const float*)d_in[6];
  float* out = (float*)d_out;

  // ws layout: hbuf[2 bufs][2 planes hi/lo][NB*NH] u16, then split weights
  unsigned short* hbuf = (unsigned short*)d_ws;
  const size_t plane = (size_t)NB * NH;                    // 131072 elems
  unsigned short* whh_hi = hbuf + 4 * plane;
  unsigned short* whh_lo = whh_hi + (size_t)NH * NH;
  unsigned short* wih_hi = whh_lo + (size_t)NH * NH;
  unsigned short* wih_lo = wih_hi + (size_t)NH * ND;
  float* bias = (float*)(wih_lo + (size_t)NH * ND);

  // h_{-1} = 0 (buf0, hi+lo planes contiguous)
  hipMemsetAsync(hbuf, 0, 2 * plane * sizeof(unsigned short), stream);
  prep_kernel<<<1024, 256, 0, stream>>>(whh, wih, bih, bhh, bho, out,
                                        whh_hi, whh_lo, wih_hi, wih_lo, bias);

  for (int t = 0; t < NT; ++t) {
    unsigned short* prev = hbuf + (size_t)(t & 1) * 2 * plane;
    unsigned short* next = hbuf + (size_t)((t + 1) & 1) * 2 * plane;
    rnn_step<<<256, 128, 0, stream>>>(whh_hi, whh_lo, wih_hi, wih_lo, bias, x, who,
                                      prev, prev + plane, next, next + plane, out, t);
  }
}